// Round 5
// baseline (408.357 us; speedup 1.0000x reference)
//
#include <hip/hip_runtime.h>
#include <math.h>

// Problem constants
#define N_ROWS   131072      // 32*64*64 pixels
#define DIM      64
#define KCODES   1024
#define HWSZ     4096
#define CHW      262144
#define OUT_ELEMS 8388608

#define TH        2e-4f      // near-tie threshold (covers ref fp32 noise + bf16-split approx error)
#define CAP_PAIRS 32768

// d_ws layout (bytes)
#define WS_WSUM   0              // f32[1024]
#define WS_WH     4096           // ushort[1024*64] bf16 codebook
#define WS_AIDX   135168         // int[131072] approx argmin
#define WS_KEY    659456         // u64[131072] exact-refine keys (bits(dk)<<32|k)
#define WS_PCNT   1708032        // u32 pair counter (memset 0 per launch)
#define WS_PAIRS  1708096        // u32[CAP_PAIRS] packed (row<<10|code)
#define WS_BLOSS  1839168        // f32[512] loss partials

typedef __attribute__((ext_vector_type(8)))  short bf16x8;
typedef __attribute__((ext_vector_type(16))) float f32x16;

// ---------------------------------------------------------------------------
static __device__ __forceinline__ unsigned short f32_to_bf16(float f) {
    union { float f; unsigned u; } v; v.f = f;
    unsigned r = v.u + 0x7FFFu + ((v.u >> 16) & 1u);   // RNE
    return (unsigned short)(r >> 16);
}
static __device__ __forceinline__ float bf16_to_f32(unsigned short h) {
    union { unsigned u; float f; } v; v.u = ((unsigned)h) << 16;
    return v.f;
}

// numpy pairwise sum of squares, n=64 — bit-exact np.sum(v**2, axis=-1)
__device__ __forceinline__ float np_sumsq64(const float* v) {
#pragma clang fp contract(off)
    float r[8];
#pragma unroll
    for (int j = 0; j < 8; ++j) r[j] = v[j] * v[j];
#pragma unroll
    for (int i = 8; i < 64; i += 8) {
#pragma unroll
        for (int j = 0; j < 8; ++j) {
            float p = v[i + j] * v[i + j];
            r[j] = r[j] + p;
        }
    }
    float s01 = r[0] + r[1], s23 = r[2] + r[3];
    float s45 = r[4] + r[5], s67 = r[6] + r[7];
    return (s01 + s23) + (s45 + s67);
}

// ---------------------------------------------------------------------------
// Kernel A: wsum (np-pairwise, bit-exact b_k) + bf16 codebook
// ---------------------------------------------------------------------------
__global__ __launch_bounds__(256) void vq_prep(const float* __restrict__ w,
                                               float* __restrict__ wsum,
                                               unsigned short* __restrict__ wh) {
    int k = blockIdx.x * blockDim.x + threadIdx.x;   // grid 4*256 = 1024
    const float* wr = w + k * DIM;
    float wv[DIM];
#pragma unroll
    for (int d = 0; d < DIM; ++d) wv[d] = wr[d];
    wsum[k] = np_sumsq64(wv);
#pragma unroll
    for (int d = 0; d < DIM; ++d) wh[k * DIM + d] = f32_to_bf16(wv[d]);
}

// ---------------------------------------------------------------------------
// Kernel B: MFMA argmin. 1024 blocks x 256 thr (4 waves); 128 rows/block,
// 32 rows/wave via 32x32x16 bf16 MFMA. Phase 1: best/sec/idx per row.
// Phase 2: re-sweep, append candidates (t <= best+TH) of flagged rows.
// ---------------------------------------------------------------------------
__global__ __launch_bounds__(256, 2) void vq_argmin(
        const float* __restrict__ inp,
        const float* __restrict__ wsum,
        const unsigned short* __restrict__ wh,
        int* __restrict__ aidx,
        unsigned long long* __restrict__ key,
        unsigned int* __restrict__ paircnt,
        unsigned int* __restrict__ pairs) {
    __shared__ float sx[128 * 68];             // x tile fp32 (stride 68: 16B-aligned rows)
    __shared__ unsigned short swt[2048 * 8];   // w tile, frag-interleaved: [cc*4+kc][lane] x 8 bf16
    __shared__ float sws[256];

    const int tid  = threadIdx.x;
    const int lane = tid & 63;
    const int wid  = tid >> 6;         // 0..3
    const int m    = lane & 31;        // MFMA row-class / code-class
    const int q    = lane >> 5;        // 0/1
    const int row0 = blockIdx.x * 128;
    const int b    = row0 >> 12;       // 4096/128=32: block never crosses batch
    const int hw0  = row0 & 4095;

    // ---- stage X tile: 128 rows x 64 d, coalesced per-d ----
    {
        const int r  = tid & 127;
        const int d0 = tid >> 7;       // 0 or 1
        const float* src = inp + (size_t)b * CHW + hw0 + r;
        for (int d = d0; d < DIM; d += 2)
            sx[r * 68 + d] = src[(size_t)d * HWSZ];
    }
    __syncthreads();

    // ---- build A-frags: xh, xl (split bf16), rows = wid*32 + m ----
    bf16x8 ah[4], al[4];
    {
        const float* xrow = sx + (wid * 32 + m) * 68;
#pragma unroll
        for (int kc = 0; kc < 4; ++kc) {
            const int dbase = kc * 16 + q * 8;
            bf16x8 h, l;
#pragma unroll
            for (int j = 0; j < 8; ++j) {
                float xv = xrow[dbase + j];
                unsigned short hh = f32_to_bf16(xv);
                float rem = xv - bf16_to_f32(hh);
                h[j] = (short)hh;
                l[j] = (short)f32_to_bf16(rem);
            }
            ah[kc] = h; al[kc] = l;
        }
    }

    float best[16], sec[16];
    int   bidx[16];
#pragma unroll
    for (int r = 0; r < 16; ++r) { best[r] = 1e30f; sec[r] = 1e30f; bidx[r] = 0; }

    // ================= phase 1: full sweep, best/sec/idx =================
    for (int tile = 0; tile < 4; ++tile) {
        __syncthreads();
        {   // stage 256 codes -> frag-interleaved LDS (coalesced global reads)
            const unsigned short* gsrc = wh + (size_t)(tile * 256) * DIM;
#pragma unroll
            for (int it = 0; it < 8; ++it) {
                int is   = it * 256 + tid;          // 0..2047 16B chunks
                int code = is >> 3;                 // 0..255
                int part = is & 7;                  // 8 bf16 within code
                int kc   = part >> 1, q2 = part & 1;
                int cc   = code >> 5,  cl = code & 31;
                uint4 v = *(const uint4*)(gsrc + is * 8);
                *(uint4*)(swt + (((cc * 4 + kc) * 64) + q2 * 32 + cl) * 8) = v;
            }
            sws[tid] = wsum[tile * 256 + tid];
        }
        __syncthreads();

        for (int cc = 0; cc < 8; ++cc) {
            bf16x8 bf[4];
#pragma unroll
            for (int kc = 0; kc < 4; ++kc)
                bf[kc] = *(const bf16x8*)(swt + ((cc * 4 + kc) * 64 + lane) * 8);
            f32x16 acc0 = {0.f}, acc1 = {0.f};
            acc0 = __builtin_amdgcn_mfma_f32_32x32x16_bf16(ah[0], bf[0], acc0, 0, 0, 0);
            acc1 = __builtin_amdgcn_mfma_f32_32x32x16_bf16(ah[1], bf[1], acc1, 0, 0, 0);
            acc0 = __builtin_amdgcn_mfma_f32_32x32x16_bf16(ah[2], bf[2], acc0, 0, 0, 0);
            acc1 = __builtin_amdgcn_mfma_f32_32x32x16_bf16(ah[3], bf[3], acc1, 0, 0, 0);
            acc0 = __builtin_amdgcn_mfma_f32_32x32x16_bf16(al[0], bf[0], acc0, 0, 0, 0);
            acc1 = __builtin_amdgcn_mfma_f32_32x32x16_bf16(al[1], bf[1], acc1, 0, 0, 0);
            acc0 = __builtin_amdgcn_mfma_f32_32x32x16_bf16(al[2], bf[2], acc0, 0, 0, 0);
            acc1 = __builtin_amdgcn_mfma_f32_32x32x16_bf16(al[3], bf[3], acc1, 0, 0, 0);

            const float wsv  = sws[cc * 32 + m];
            const int  kcode = tile * 256 + cc * 32 + m;
#pragma unroll
            for (int r = 0; r < 16; ++r) {
                float v = acc0[r] + acc1[r];
                float t = __builtin_fmaf(v, -2.0f, wsv);
                bool  c = t < best[r];
                sec[r]  = fminf(sec[r], fmaxf(t, best[r]));
                best[r] = fminf(best[r], t);
                bidx[r] = c ? kcode : bidx[r];
            }
        }
    }

    // ---- cross-lane reduce over the 32 code-classes (xor within half) ----
#pragma unroll
    for (int ms = 1; ms <= 16; ms <<= 1) {
#pragma unroll
        for (int r = 0; r < 16; ++r) {
            float ob = __shfl_xor(best[r], ms, 64);
            float os = __shfl_xor(sec[r],  ms, 64);
            int   oi = __shfl_xor(bidx[r], ms, 64);
            sec[r]  = fminf(fminf(sec[r], os), fmaxf(best[r], ob));
            bool  c = ob < best[r];
            best[r] = fminf(best[r], ob);
            bidx[r] = c ? oi : bidx[r];
        }
    }

    // ---- write approx idx + init keys; compute phase-2 limits ----
    if (m < 16) {
        const int r  = m;
        const int rr = row0 + wid * 32 + (r & 3) + 8 * (r >> 2) + 4 * q;
        aidx[rr] = bidx[r];
        key[rr]  = ~0ull;
    }
    float limit2[16];
    bool hasflag = false;
#pragma unroll
    for (int r = 0; r < 16; ++r) {
        bool fl = (sec[r] - best[r]) < TH;
        limit2[r] = fl ? best[r] + TH : -1e30f;
        hasflag |= fl;
    }
    const bool wave_go = __any((int)hasflag);

    // ================= phase 2: candidate append for flagged rows =========
    for (int tile = 0; tile < 4; ++tile) {
        __syncthreads();
        {
            const unsigned short* gsrc = wh + (size_t)(tile * 256) * DIM;
#pragma unroll
            for (int it = 0; it < 8; ++it) {
                int is   = it * 256 + tid;
                int code = is >> 3;
                int part = is & 7;
                int kc   = part >> 1, q2 = part & 1;
                int cc   = code >> 5,  cl = code & 31;
                uint4 v = *(const uint4*)(gsrc + is * 8);
                *(uint4*)(swt + (((cc * 4 + kc) * 64) + q2 * 32 + cl) * 8) = v;
            }
            sws[tid] = wsum[tile * 256 + tid];
        }
        __syncthreads();
        if (!wave_go) continue;

        for (int cc = 0; cc < 8; ++cc) {
            bf16x8 bf[4];
#pragma unroll
            for (int kc = 0; kc < 4; ++kc)
                bf[kc] = *(const bf16x8*)(swt + ((cc * 4 + kc) * 64 + lane) * 8);
            f32x16 acc0 = {0.f}, acc1 = {0.f};
            acc0 = __builtin_amdgcn_mfma_f32_32x32x16_bf16(ah[0], bf[0], acc0, 0, 0, 0);
            acc1 = __builtin_amdgcn_mfma_f32_32x32x16_bf16(ah[1], bf[1], acc1, 0, 0, 0);
            acc0 = __builtin_amdgcn_mfma_f32_32x32x16_bf16(ah[2], bf[2], acc0, 0, 0, 0);
            acc1 = __builtin_amdgcn_mfma_f32_32x32x16_bf16(ah[3], bf[3], acc1, 0, 0, 0);
            acc0 = __builtin_amdgcn_mfma_f32_32x32x16_bf16(al[0], bf[0], acc0, 0, 0, 0);
            acc1 = __builtin_amdgcn_mfma_f32_32x32x16_bf16(al[1], bf[1], acc1, 0, 0, 0);
            acc0 = __builtin_amdgcn_mfma_f32_32x32x16_bf16(al[2], bf[2], acc0, 0, 0, 0);
            acc1 = __builtin_amdgcn_mfma_f32_32x32x16_bf16(al[3], bf[3], acc1, 0, 0, 0);

            const float wsv  = sws[cc * 32 + m];
            const int  kcode = tile * 256 + cc * 32 + m;
#pragma unroll
            for (int r = 0; r < 16; ++r) {
                float v = acc0[r] + acc1[r];
                float t = __builtin_fmaf(v, -2.0f, wsv);
                if (t <= limit2[r]) {
                    unsigned pos = atomicAdd(paircnt, 1u);
                    if (pos < CAP_PAIRS) {
                        int rr = row0 + wid * 32 + (r & 3) + 8 * (r >> 2) + 4 * q;
                        pairs[pos] = ((unsigned)rr << 10) | (unsigned)kcode;
                    }
                }
            }
        }
    }
}

// ---------------------------------------------------------------------------
// Kernel C: exact re-check of candidate pairs (bit-exact ref emulation).
// One lane per (row, code) pair; atomicMin packed (bits(dk)<<32|k).
// ---------------------------------------------------------------------------
__global__ __launch_bounds__(64) void vq_exact(
        const float* __restrict__ inp,
        const float* __restrict__ weight,
        const float* __restrict__ wsum,
        const unsigned int* __restrict__ paircnt,
        const unsigned int* __restrict__ pairs,
        unsigned long long* __restrict__ key) {
    unsigned i   = blockIdx.x * 64 + threadIdx.x;
    unsigned cnt = *paircnt;
    if (cnt > CAP_PAIRS) cnt = CAP_PAIRS;
    if (i >= cnt) return;
    unsigned p = pairs[i];
    int rr = (int)(p >> 10), k = (int)(p & 1023);
    int b = rr >> 12, hw = rr & 4095;
    const float* xb = inp + (size_t)b * CHW + hw;
    float x[DIM];
#pragma unroll
    for (int d = 0; d < DIM; ++d) x[d] = xb[(size_t)d * HWSZ];
    const float a = np_sumsq64(x);
    const float* wr = weight + k * DIM;
    float c = 0.f;
#pragma unroll
    for (int d = 0; d < DIM; ++d) c = __builtin_fmaf(x[d], wr[d], c);
    float s, dk;
    {
#pragma clang fp contract(off)
        s  = a + wsum[k];
        dk = s - 2.0f * c;
    }
    unsigned long long kv =
        (((unsigned long long)__float_as_uint(dk)) << 32) | (unsigned)k;
    atomicMin(&key[rr], kv);   // dk>0: fp32 bits monotone; low bits: first-index ties
}

// ---------------------------------------------------------------------------
// Kernel D: epilogue — final idx, gather w, write out NCHW, loss partials
// ---------------------------------------------------------------------------
__global__ __launch_bounds__(256) void vq_epilogue(
        const float* __restrict__ inp,
        const float* __restrict__ weight,
        const int* __restrict__ aidx,
        const unsigned long long* __restrict__ key,
        float* __restrict__ out,
        float* __restrict__ idx_out,
        float* __restrict__ block_loss) {
    const int n  = blockIdx.x * 256 + threadIdx.x;   // grid exact: 512*256
    const int b  = n >> 12;
    const int hw = n & 4095;
    unsigned long long kv = key[n];
    const int k = (kv != ~0ull) ? (int)(kv & 1023u) : aidx[n];

    const float* xb = inp + (size_t)b * CHW + hw;
    const float* wr = weight + k * DIM;
    float* ob = out + (size_t)b * CHW + hw;
    float ls = 0.f;
#pragma unroll
    for (int d = 0; d < DIM; ++d) {
        const float wv = wr[d];
        const float xv = xb[(size_t)d * HWSZ];
        ob[(size_t)d * HWSZ] = wv;
        const float df = wv - xv;
        ls = fmaf(df, df, ls);
    }
    idx_out[n] = (float)k;

    __shared__ float red[4];
#pragma unroll
    for (int off = 32; off > 0; off >>= 1) ls += __shfl_down(ls, off, 64);
    const int lane = threadIdx.x & 63;
    const int wid  = threadIdx.x >> 6;
    if (lane == 0) red[wid] = ls;
    __syncthreads();
    if (threadIdx.x == 0)
        block_loss[blockIdx.x] = (red[0] + red[1]) + (red[2] + red[3]);
}

// ---------------------------------------------------------------------------
// Kernel E: reduce 512 partials -> loss = 1.25 * mean((q-x)^2)
// ---------------------------------------------------------------------------
__global__ __launch_bounds__(256) void vq_loss_reduce(const float* __restrict__ bl,
                                                      float* __restrict__ loss_out) {
    double s = 0.0;
    for (int i = threadIdx.x; i < 512; i += 256) s += (double)bl[i];
    __shared__ double red[4];
#pragma unroll
    for (int off = 32; off > 0; off >>= 1) s += __shfl_down(s, off, 64);
    const int lane = threadIdx.x & 63;
    const int wid  = threadIdx.x >> 6;
    if (lane == 0) red[wid] = s;
    __syncthreads();
    if (threadIdx.x == 0) {
        const double total = (red[0] + red[1]) + (red[2] + red[3]);
        loss_out[0] = (float)(1.25 * total / (double)OUT_ELEMS);
    }
}

// ---------------------------------------------------------------------------
extern "C" void kernel_launch(void* const* d_in, const int* in_sizes, int n_in,
                              void* d_out, int out_size, void* d_ws, size_t ws_size,
                              hipStream_t stream) {
    const float* inp    = (const float*)d_in[0];
    const float* weight = (const float*)d_in[1];

    float* out_q    = (float*)d_out;
    float* out_loss = (float*)d_out + OUT_ELEMS;
    float* out_idx  = (float*)d_out + OUT_ELEMS + 1;

    char* ws = (char*)d_ws;
    float*              wsum  = (float*)(ws + WS_WSUM);
    unsigned short*     wh    = (unsigned short*)(ws + WS_WH);
    int*                aidx  = (int*)(ws + WS_AIDX);
    unsigned long long* key   = (unsigned long long*)(ws + WS_KEY);
    unsigned int*       pcnt  = (unsigned int*)(ws + WS_PCNT);
    unsigned int*       pairs = (unsigned int*)(ws + WS_PAIRS);
    float*              bloss = (float*)(ws + WS_BLOSS);

    vq_prep<<<4, 256, 0, stream>>>(weight, wsum, wh);
    hipMemsetAsync(pcnt, 0, sizeof(unsigned int), stream);
    vq_argmin<<<1024, 256, 0, stream>>>(inp, wsum, wh, aidx, key, pcnt, pairs);
    vq_exact<<<CAP_PAIRS / 64, 64, 0, stream>>>(inp, weight, wsum, pcnt, pairs, key);
    vq_epilogue<<<512, 256, 0, stream>>>(inp, weight, aidx, key,
                                         out_q, out_idx, bloss);
    vq_loss_reduce<<<1, 256, 0, stream>>>(bloss, out_loss);
}